// Round 6
// baseline (109.821 us; speedup 1.0000x reference)
//
#include <hip/hip_runtime.h>
#include <hip/hip_bf16.h>

// Problem constants (from reference setup_inputs)
#define B_  16
#define S_  1024
#define D_  300
#define K_  64           // hidden_set_size == compressed dim
#define O_  256          // outputs per batch
#define M_  (B_*S_)      // 16384 rows (b,s)

typedef __attribute__((ext_vector_type(8)))  short s8b;    // 8 x bf16 (4 VGPRs)
typedef __attribute__((ext_vector_type(4)))  float f32x4;
typedef __attribute__((ext_vector_type(16))) float f32x16;

#define MFMA16(a,b,c) __builtin_amdgcn_mfma_f32_16x16x32_bf16((a),(b),(c),0,0,0)
#define MFMA32(a,b,c) __builtin_amdgcn_mfma_f32_32x32x16_bf16((a),(b),(c),0,0,0)

// Direct global->LDS DMA, 16 B per lane.  Global addr is PER-LANE, LDS dest
// is wave-uniform base + lane*16 (m104/m108 semantics).
typedef __attribute__((address_space(1))) const void gas_void;
typedef __attribute__((address_space(3))) void las_void;
#define GLOAD16(g, l) __builtin_amdgcn_global_load_lds( \
    (gas_void*)(g), (las_void*)(l), 16, 0, 0)

__device__ __forceinline__ unsigned short bf16_bits(float f) {
    return __builtin_bit_cast(unsigned short, __float2bfloat16(f));
}

// Pack two float4s into an s8b bf16 fragment (same rounding everywhere).
__device__ __forceinline__ s8b pack8(float4 f0, float4 f1) {
    union { unsigned short us[8]; s8b v; } pk;
    pk.us[0]=bf16_bits(f0.x); pk.us[1]=bf16_bits(f0.y);
    pk.us[2]=bf16_bits(f0.z); pk.us[3]=bf16_bits(f0.w);
    pk.us[4]=bf16_bits(f1.x); pk.us[5]=bf16_bits(f1.y);
    pk.us[6]=bf16_bits(f1.z); pk.us[7]=bf16_bits(f1.w);
    return pk.v;
}

// relu-max over the 32 in-lane n-values of an MFMA32 acc pair.
__device__ __forceinline__ float maxreduce32(const f32x16& a0, const f32x16& a1) {
    float m0 = fmaxf(fmaxf(a0[0], a0[1]), a0[2]);
    m0 = fmaxf(fmaxf(m0, a0[3]), a0[4]);
    m0 = fmaxf(fmaxf(m0, a0[5]), a0[6]);
    m0 = fmaxf(m0, a0[7]);
    float m1 = fmaxf(fmaxf(a0[8], a0[9]), a0[10]);
    m1 = fmaxf(fmaxf(m1, a0[11]), a0[12]);
    m1 = fmaxf(fmaxf(m1, a0[13]), a0[14]);
    m1 = fmaxf(m1, a0[15]);
    float m2 = fmaxf(fmaxf(a1[0], a1[1]), a1[2]);
    m2 = fmaxf(fmaxf(m2, a1[3]), a1[4]);
    m2 = fmaxf(fmaxf(m2, a1[5]), a1[6]);
    m2 = fmaxf(m2, a1[7]);
    float m3 = fmaxf(fmaxf(a1[8], a1[9]), a1[10]);
    m3 = fmaxf(fmaxf(m3, a1[11]), a1[12]);
    m3 = fmaxf(fmaxf(m3, a1[13]), a1[14]);
    m3 = fmaxf(m3, a1[15]);
    return fmaxf(fmaxf(fmaxf(m0, m1), fmaxf(m2, m3)), 0.0f);
}

// ---------------------------------------------------------------------------
// Kernel 1 (merged head): three block roles in ONE dispatch (proven R2).
//   blocks [0, 1024)      : compress GEMM  Xc = bf16(Xs @ W^T + b)
//   blocks [1024, 1536)   : H f32 -> bf16 into Hb (amortized 32x by k_fused)
//   block  1536           : out[16*256] = 0 (k_fused accumulates atomically)
// ---------------------------------------------------------------------------
#define C_BLK 1024    // M_/16 compress blocks
#define H_BLK 512     // 256*64*64/8/256 convert blocks

__global__ __launch_bounds__(256) void k_head(
        const float* __restrict__ Xs,
        const float* __restrict__ W,
        const float* __restrict__ bias,
        const float* __restrict__ H,
        __hip_bfloat16* __restrict__ Xc,
        __hip_bfloat16* __restrict__ Hb,
        float* __restrict__ out) {
    int bx = blockIdx.x, tid = threadIdx.x;
    if (bx >= C_BLK) {
        if (bx < C_BLK + H_BLK) {            // H flat f32 -> bf16
            int g = ((bx - C_BLK) * 256 + tid) * 8;
            float4 f0 = *(const float4*)(H + g);
            float4 f1 = *(const float4*)(H + g + 4);
            *(uint4*)(Hb + g) = __builtin_bit_cast(uint4, pack8(f0, f1));
        } else {                             // zero out[4096]
            float4 z = {0.f,0.f,0.f,0.f};
            float4* o4 = (float4*)out;
#pragma unroll
            for (int i = 0; i < 4; ++i) o4[tid * 4 + i] = z;
        }
        return;
    }

    int w    = tid >> 6, lane = tid & 63;
    int q    = lane >> 4, r = lane & 15;
    int row0 = bx * 16;
    int col0 = w * 16;

    f32x4 acc0 = {0.f,0.f,0.f,0.f}, acc1 = {0.f,0.f,0.f,0.f};
    const float* arow = Xs + (size_t)(row0 + r) * D_;
    const float* brow = W  + (size_t)(col0 + r) * D_;
    const float4 z4 = {0.f,0.f,0.f,0.f};

#pragma unroll
    for (int ks = 0; ks < 10; ++ks) {
        int k0 = ks * 32 + q * 8;
        float4 a0 = (k0     < D_) ? *(const float4*)(arow + k0)     : z4;
        float4 a1 = (k0 + 4 < D_) ? *(const float4*)(arow + k0 + 4) : z4;
        float4 b0 = (k0     < D_) ? *(const float4*)(brow + k0)     : z4;
        float4 b1 = (k0 + 4 < D_) ? *(const float4*)(brow + k0 + 4) : z4;
        s8b av = pack8(a0, a1);
        s8b bv = pack8(b0, b1);
        if (ks & 1) acc1 = MFMA16(av, bv, acc1);
        else        acc0 = MFMA16(av, bv, acc0);
    }
    // C/D layout: col = lane&15 (out-k), row = quad*4 + i (bs)
#pragma unroll
    for (int i = 0; i < 4; ++i) {
        int orow = row0 + q * 4 + i;
        int c    = col0 + r;
        Xc[(size_t)orow * K_ + c] =
            __float2bfloat16(acc0[i] + acc1[i] + bias[c]);
    }
}

// ---------------------------------------------------------------------------
// Kernel 2: fused bipartite GEMM + relu + max-over-n + sum-over-s.
// T3+T4 staging rebuild (R5 post-mortem: the schedule inside the slice loop
// was never the constraint — the global->VGPR->ds_write + full-drain
// __syncthreads publish per slice was).  Now:
//   - 4-deep LDS ring (4 x 8 KB), filled by global_load_lds width=16:
//     ONE instruction per wave per slice, no VGPR round-trip, no ds_write.
//   - counted vmcnt, never drained in-loop: prologue issues slices 0-2;
//     slice s does  s_waitcnt vmcnt(2) -> s_barrier -> issue s+3 ->
//     ds_read/MFMA/reduce.  One barrier per slice; 3 loads in flight.
//   - LDS is LINEAR [64][64] per slice (gload_lds writes base+lane*16);
//     bank conflicts broken by chunk-XOR swizzle applied on the global
//     SOURCE address (rule #21): LDS slot (row, c) holds global chunk
//     c^(row&7); reads use chunk (2ks+half)^(l31&7) -> all 8 bank groups
//     hit, 8-cyc = data minimum, conflict-free.
//     Source fold: lane l of wave w fetches chunk (l&7)^(l>>3) of row
//     8w+(l>>3) (slice/wave offsets vanish mod 8).
//   - rules #18/#21 fencing: ""::"memory" asm + sched_barrier(0) after each
//     raw s_barrier so ds_reads can't hoist across; vmcnt asm has "memory".
// MFMA/reduce math byte-identical to R4.  setprio kept (counted-vmcnt
// phase schedule = T5's paying regime).
// Grid: 16 batches x 32 o-octets x 2 s-halves = 1024 blocks; 8 waves;
// LDS 32,768 B.
// ---------------------------------------------------------------------------
__global__ __launch_bounds__(512, 4) void k_fused(
        const __hip_bfloat16* __restrict__ Xc,
        const __hip_bfloat16* __restrict__ Hb,
        float* __restrict__ out) {
    __shared__ __hip_bfloat16 lx[4][64 * 64];   // 4 x 8,192 B ring
    int tid   = threadIdx.x;
    int w     = tid >> 6, lane = tid & 63;
    int half  = lane >> 5, l31 = lane & 31;
    int xm    = l31 & 7;                        // read-side XOR mask
    int bx    = blockIdx.x;
    int batch = bx >> 6;          // 0..15
    int oq    = (bx >> 1) & 31;   // 0..31
    int sh    = bx & 1;           // 0..1 : which 512-row half
    int o     = oq * 8 + w;       // this wave's output column

    // Preload A fragments (Hb, this wave's o): 2 n-tiles x 4 k-steps.
    // A layout: row = lane&31 (n), k = ks*16 + (lane>>5)*8 + j.
    s8b af[2][4];
#pragma unroll
    for (int nt = 0; nt < 2; ++nt) {
        const __hip_bfloat16* hrow =
            Hb + (size_t)(o * 64 + nt * 32 + l31) * 64 + half * 8;
#pragma unroll
        for (int ks = 0; ks < 4; ++ks)
            af[nt][ks] = __builtin_bit_cast(s8b, *(const uint4*)(hrow + ks * 16));
    }
    // Drain all plain vmem loads so in-loop vmcnt counts ONLY gload_lds.
    asm volatile("s_waitcnt vmcnt(0)" ::: "memory");

    const __hip_bfloat16* xbase =
        Xc + ((size_t)batch * S_ + (size_t)sh * 512) * K_;

    // Per-lane staging source (element offset inside a slice):
    // row_local = 8w + (lane>>3); global chunk = (lane&7) ^ (lane>>3).
    const __hip_bfloat16* gs =
        xbase + (size_t)(8 * w + (lane >> 3)) * K_
              + (((lane & 7) ^ (lane >> 3)) * 8);

    // Prologue: issue slices 0,1,2 into ring buffers 0,1,2.
#pragma unroll
    for (int p = 0; p < 3; ++p)
        GLOAD16(gs + (size_t)p * 64 * K_, &lx[p][w * 512]);

    float total = 0.0f;
#pragma unroll
    for (int s = 0; s < 8; ++s) {
        // Wait for own slice-s load (keep up to 2 younger in flight),
        // then barrier => ALL waves' slice-s data is in LDS.
        if      (s <= 5) asm volatile("s_waitcnt vmcnt(2)" ::: "memory");
        else if (s == 6) asm volatile("s_waitcnt vmcnt(1)" ::: "memory");
        else             asm volatile("s_waitcnt vmcnt(0)" ::: "memory");
        __builtin_amdgcn_s_barrier();
        asm volatile("" ::: "memory");          // no IR hoist across barrier
        __builtin_amdgcn_sched_barrier(0);      // no MI sched across either

        // Issue slice s+3 into buffer (s+3)&3 — safe: every wave finished
        // reading that buffer (slice s-1) before entering this barrier.
        if (s < 5)
            GLOAD16(gs + (size_t)(s + 3) * 64 * K_, &lx[(s + 3) & 3][w * 512]);

        const __hip_bfloat16* buf = lx[s & 3];
#pragma unroll
        for (int t = 0; t < 2; ++t) {
            int rr = t * 32 + l31;
            // B layout: col = lane&31 (bs row rr), k = (lane>>5)*8 + j;
            // logical chunk 2ks+half lives at LDS slot (2ks+half)^xm.
            s8b bf[4];
#pragma unroll
            for (int ks = 0; ks < 4; ++ks)
                bf[ks] = __builtin_bit_cast(s8b,
                    *(const uint4*)(&buf[rr * K_ + (((2 * ks + half) ^ xm) * 8)]));

            f32x16 a0 = {0.f,0.f,0.f,0.f,0.f,0.f,0.f,0.f,
                         0.f,0.f,0.f,0.f,0.f,0.f,0.f,0.f};
            f32x16 a1 = a0;
            __builtin_amdgcn_s_setprio(1);
#pragma unroll
            for (int ks = 0; ks < 4; ++ks) {
                a0 = MFMA32(af[0][ks], bf[ks], a0);
                a1 = MFMA32(af[1][ks], bf[ks], a1);
            }
            __builtin_amdgcn_s_setprio(0);

            float v = maxreduce32(a0, a1);
            v = fmaxf(v, __shfl_xor(v, 32));   // other half's 32 n-rows
            total += v;                        // lane's bs col = rr (replicated)
        }
    }
    // Sum over the 32 bs columns (halves hold identical totals).
    total += __shfl_xor(total, 1);
    total += __shfl_xor(total, 2);
    total += __shfl_xor(total, 4);
    total += __shfl_xor(total, 8);
    total += __shfl_xor(total, 16);
    if (lane == 0) atomicAdd(out + batch * O_ + o, total);
}

// ---------------------------------------------------------------------------
extern "C" void kernel_launch(void* const* d_in, const int* in_sizes, int n_in,
                              void* d_out, int out_size, void* d_ws, size_t ws_size,
                              hipStream_t stream) {
    const float* Xs   = (const float*)d_in[0];   // [16,1024,300]
    const float* W    = (const float*)d_in[1];   // [64,300]
    const float* bias = (const float*)d_in[2];   // [64]
    const float* H    = (const float*)d_in[3];   // [256,64,64]
    float* out = (float*)d_out;                  // [16,256] f32

    char* ws = (char*)d_ws;
    __hip_bfloat16* Hb = (__hip_bfloat16*)(ws);            // 2,097,152 B
    __hip_bfloat16* Xc = (__hip_bfloat16*)(ws + 2097152);  // 2,097,152 B

    k_head <<<C_BLK + H_BLK + 1, 256, 0, stream>>>(Xs, W, bias, H, Xc, Hb, out);
    k_fused<<<B_ * (O_ / 8) * 2, 512, 0, stream>>>(Xc, Hb, out);
}

// Round 7
// 108.449 us; speedup vs baseline: 1.0127x; 1.0127x over previous
//
#include <hip/hip_runtime.h>
#include <hip/hip_bf16.h>

// Problem constants (from reference setup_inputs)
#define B_  16
#define S_  1024
#define D_  300
#define K_  64           // hidden_set_size == compressed dim
#define O_  256          // outputs per batch
#define M_  (B_*S_)      // 16384 rows (b,s)

typedef __attribute__((ext_vector_type(8)))  short s8b;    // 8 x bf16 (4 VGPRs)
typedef __attribute__((ext_vector_type(4)))  float f32x4;
typedef __attribute__((ext_vector_type(16))) float f32x16;

#define MFMA16(a,b,c) __builtin_amdgcn_mfma_f32_16x16x32_bf16((a),(b),(c),0,0,0)
#define MFMA32(a,b,c) __builtin_amdgcn_mfma_f32_32x32x16_bf16((a),(b),(c),0,0,0)

// Direct global->LDS DMA, 16 B per lane.  Global addr is PER-LANE, LDS dest
// is wave-uniform base + lane*16 (m104/m108 semantics).
typedef __attribute__((address_space(1))) const void gas_void;
typedef __attribute__((address_space(3))) void las_void;
#define GLOAD16(g, l) __builtin_amdgcn_global_load_lds( \
    (gas_void*)(g), (las_void*)(l), 16, 0, 0)

__device__ __forceinline__ unsigned short bf16_bits(float f) {
    return __builtin_bit_cast(unsigned short, __float2bfloat16(f));
}

// Pack two float4s into an s8b bf16 fragment (same rounding everywhere).
__device__ __forceinline__ s8b pack8(float4 f0, float4 f1) {
    union { unsigned short us[8]; s8b v; } pk;
    pk.us[0]=bf16_bits(f0.x); pk.us[1]=bf16_bits(f0.y);
    pk.us[2]=bf16_bits(f0.z); pk.us[3]=bf16_bits(f0.w);
    pk.us[4]=bf16_bits(f1.x); pk.us[5]=bf16_bits(f1.y);
    pk.us[6]=bf16_bits(f1.z); pk.us[7]=bf16_bits(f1.w);
    return pk.v;
}

// relu-max over the 32 in-lane n-values of an MFMA32 acc pair.
__device__ __forceinline__ float maxreduce32(const f32x16& a0, const f32x16& a1) {
    float m0 = fmaxf(fmaxf(a0[0], a0[1]), a0[2]);
    m0 = fmaxf(fmaxf(m0, a0[3]), a0[4]);
    m0 = fmaxf(fmaxf(m0, a0[5]), a0[6]);
    m0 = fmaxf(m0, a0[7]);
    float m1 = fmaxf(fmaxf(a0[8], a0[9]), a0[10]);
    m1 = fmaxf(fmaxf(m1, a0[11]), a0[12]);
    m1 = fmaxf(fmaxf(m1, a0[13]), a0[14]);
    m1 = fmaxf(m1, a0[15]);
    float m2 = fmaxf(fmaxf(a1[0], a1[1]), a1[2]);
    m2 = fmaxf(fmaxf(m2, a1[3]), a1[4]);
    m2 = fmaxf(fmaxf(m2, a1[5]), a1[6]);
    m2 = fmaxf(m2, a1[7]);
    float m3 = fmaxf(fmaxf(a1[8], a1[9]), a1[10]);
    m3 = fmaxf(fmaxf(m3, a1[11]), a1[12]);
    m3 = fmaxf(fmaxf(m3, a1[13]), a1[14]);
    m3 = fmaxf(m3, a1[15]);
    return fmaxf(fmaxf(fmaxf(m0, m1), fmaxf(m2, m3)), 0.0f);
}

// ---------------------------------------------------------------------------
// Kernel 1 (merged head): three block roles in ONE dispatch (proven R2).
//   blocks [0, 1024)      : compress GEMM  Xc = bf16(Xs @ W^T + b)
//   blocks [1024, 1536)   : H f32 -> bf16 into Hb (amortized 32x by k_fused)
//   block  1536           : out[16*256] = 0 (k_fused accumulates atomically)
// ---------------------------------------------------------------------------
#define C_BLK 1024    // M_/16 compress blocks
#define H_BLK 512     // 256*64*64/8/256 convert blocks

__global__ __launch_bounds__(256) void k_head(
        const float* __restrict__ Xs,
        const float* __restrict__ W,
        const float* __restrict__ bias,
        const float* __restrict__ H,
        __hip_bfloat16* __restrict__ Xc,
        __hip_bfloat16* __restrict__ Hb,
        float* __restrict__ out) {
    int bx = blockIdx.x, tid = threadIdx.x;
    if (bx >= C_BLK) {
        if (bx < C_BLK + H_BLK) {            // H flat f32 -> bf16
            int g = ((bx - C_BLK) * 256 + tid) * 8;
            float4 f0 = *(const float4*)(H + g);
            float4 f1 = *(const float4*)(H + g + 4);
            *(uint4*)(Hb + g) = __builtin_bit_cast(uint4, pack8(f0, f1));
        } else {                             // zero out[4096]
            float4 z = {0.f,0.f,0.f,0.f};
            float4* o4 = (float4*)out;
#pragma unroll
            for (int i = 0; i < 4; ++i) o4[tid * 4 + i] = z;
        }
        return;
    }

    int w    = tid >> 6, lane = tid & 63;
    int q    = lane >> 4, r = lane & 15;
    int row0 = bx * 16;
    int col0 = w * 16;

    f32x4 acc0 = {0.f,0.f,0.f,0.f}, acc1 = {0.f,0.f,0.f,0.f};
    const float* arow = Xs + (size_t)(row0 + r) * D_;
    const float* brow = W  + (size_t)(col0 + r) * D_;
    const float4 z4 = {0.f,0.f,0.f,0.f};

#pragma unroll
    for (int ks = 0; ks < 10; ++ks) {
        int k0 = ks * 32 + q * 8;
        float4 a0 = (k0     < D_) ? *(const float4*)(arow + k0)     : z4;
        float4 a1 = (k0 + 4 < D_) ? *(const float4*)(arow + k0 + 4) : z4;
        float4 b0 = (k0     < D_) ? *(const float4*)(brow + k0)     : z4;
        float4 b1 = (k0 + 4 < D_) ? *(const float4*)(brow + k0 + 4) : z4;
        s8b av = pack8(a0, a1);
        s8b bv = pack8(b0, b1);
        if (ks & 1) acc1 = MFMA16(av, bv, acc1);
        else        acc0 = MFMA16(av, bv, acc0);
    }
    // C/D layout: col = lane&15 (out-k), row = quad*4 + i (bs)
#pragma unroll
    for (int i = 0; i < 4; ++i) {
        int orow = row0 + q * 4 + i;
        int c    = col0 + r;
        Xc[(size_t)orow * K_ + c] =
            __float2bfloat16(acc0[i] + acc1[i] + bias[c]);
    }
}

// ---------------------------------------------------------------------------
// Kernel 2: fused bipartite GEMM + relu + max-over-n + sum-over-s.
// ZERO-BARRIER body (R4/R5/R6 post-mortem: four different slice schedules
// all pinned at 38% MfmaUtil; the shared binder is the per-slice block-wide
// barrier lockstep that phase-aligns the 4 waves/SIMD, so the MFMA pipe
// oscillates at ~40% duty).  Now the block's ENTIRE 512-row bs-half (64 KB)
// is staged once via 8 global_load_lds per wave, ONE barrier, then 16
// t-iterations of free-running compute: no wave coupling, compiler free to
// pipeline iter t+1's ds_reads over iter t's reduce, waves free to drift
// into anti-phase on the MFMA pipe.
// LDS is linear [512][64]; bank conflicts broken by chunk-XOR swizzle on
// the global SOURCE (rule #21, proven R6): slot (row,c) holds chunk
// c^(row&7); reads use chunk (2ks+half)^(l31&7) -> all 8 bank groups.
// MFMA/reduce math byte-identical to R4.
// Occupancy: 2 blocks/CU (LDS 128 KB, VGPR<=128) = 16 waves/CU, same as all
// staged variants — the lockstep removal is the single variable.
// Grid: 16 batches x 32 o-octets x 2 s-halves = 1024 blocks; 8 waves.
// ---------------------------------------------------------------------------
__global__ __launch_bounds__(512, 4) void k_fused(
        const __hip_bfloat16* __restrict__ Xc,
        const __hip_bfloat16* __restrict__ Hb,
        float* __restrict__ out) {
    __shared__ __hip_bfloat16 lx[512 * 64];     // 65,536 B: whole bs-half
    int tid   = threadIdx.x;
    int w     = tid >> 6, lane = tid & 63;
    int half  = lane >> 5, l31 = lane & 31;
    int xm    = l31 & 7;                        // read-side XOR mask
    int bx    = blockIdx.x;
    int batch = bx >> 6;          // 0..15
    int oq    = (bx >> 1) & 31;   // 0..31
    int sh    = bx & 1;           // 0..1 : which 512-row half
    int o     = oq * 8 + w;       // this wave's output column

    const __hip_bfloat16* xbase =
        Xc + ((size_t)batch * S_ + (size_t)sh * 512) * K_;

    // Per-lane staging source (element offset inside a 64-row slice):
    // row_local = 8w + (lane>>3); global chunk = (lane&7) ^ (lane>>3)
    // (slice/wave offsets vanish mod 8, so row&7 == lane>>3).
    const __hip_bfloat16* gs =
        xbase + (size_t)(8 * w + (lane >> 3)) * K_
              + (((lane & 7) ^ (lane >> 3)) * 8);

    // Stage all 8 slices: one gload_lds per slice per wave (8 rows each).
#pragma unroll
    for (int p = 0; p < 8; ++p)
        GLOAD16(gs + (size_t)p * 64 * K_, &lx[p * 4096 + w * 512]);

    // Preload A fragments (Hb, this wave's o): 2 n-tiles x 4 k-steps.
    // A layout: row = lane&31 (n), k = ks*16 + (lane>>5)*8 + j.
    // (Issued after the gloads so HBM/L2 latency of both overlaps.)
    s8b af[2][4];
#pragma unroll
    for (int nt = 0; nt < 2; ++nt) {
        const __hip_bfloat16* hrow =
            Hb + (size_t)(o * 64 + nt * 32 + l31) * 64 + half * 8;
#pragma unroll
        for (int ks = 0; ks < 4; ++ks)
            af[nt][ks] = __builtin_bit_cast(s8b, *(const uint4*)(hrow + ks * 16));
    }

    // The ONLY barrier: all staging landed, then free-run.
    asm volatile("s_waitcnt vmcnt(0)" ::: "memory");
    __syncthreads();

    float total = 0.0f;
#pragma unroll 2
    for (int it = 0; it < 16; ++it) {
        int rr = it * 32 + l31;
        // B layout: col = lane&31 (bs row rr), k = (lane>>5)*8 + j;
        // logical chunk 2ks+half lives at LDS slot (2ks+half)^xm
        // (rr&7 == l31&7 == xm for every it since 32 % 8 == 0).
        s8b bf[4];
#pragma unroll
        for (int ks = 0; ks < 4; ++ks)
            bf[ks] = __builtin_bit_cast(s8b,
                *(const uint4*)(&lx[rr * K_ + (((2 * ks + half) ^ xm) * 8)]));

        f32x16 a0 = {0.f,0.f,0.f,0.f,0.f,0.f,0.f,0.f,
                     0.f,0.f,0.f,0.f,0.f,0.f,0.f,0.f};
        f32x16 a1 = a0;
#pragma unroll
        for (int ks = 0; ks < 4; ++ks) {
            a0 = MFMA32(af[0][ks], bf[ks], a0);
            a1 = MFMA32(af[1][ks], bf[ks], a1);
        }

        float v = maxreduce32(a0, a1);
        v = fmaxf(v, __shfl_xor(v, 32));   // other half's 32 n-rows
        total += v;                        // lane's bs col = rr (replicated)
    }

    // Sum over the 32 bs columns (halves hold identical totals).
    total += __shfl_xor(total, 1);
    total += __shfl_xor(total, 2);
    total += __shfl_xor(total, 4);
    total += __shfl_xor(total, 8);
    total += __shfl_xor(total, 16);
    if (lane == 0) atomicAdd(out + batch * O_ + o, total);
}

// ---------------------------------------------------------------------------
extern "C" void kernel_launch(void* const* d_in, const int* in_sizes, int n_in,
                              void* d_out, int out_size, void* d_ws, size_t ws_size,
                              hipStream_t stream) {
    const float* Xs   = (const float*)d_in[0];   // [16,1024,300]
    const float* W    = (const float*)d_in[1];   // [64,300]
    const float* bias = (const float*)d_in[2];   // [64]
    const float* H    = (const float*)d_in[3];   // [256,64,64]
    float* out = (float*)d_out;                  // [16,256] f32

    char* ws = (char*)d_ws;
    __hip_bfloat16* Hb = (__hip_bfloat16*)(ws);            // 2,097,152 B
    __hip_bfloat16* Xc = (__hip_bfloat16*)(ws + 2097152);  // 2,097,152 B

    k_head <<<C_BLK + H_BLK + 1, 256, 0, stream>>>(Xs, W, bias, H, Xc, Hb, out);
    k_fused<<<B_ * (O_ / 8) * 2, 512, 0, stream>>>(Xc, Hb, out);
}